// Round 1
// baseline (4961.357 us; speedup 1.0000x reference)
//
#include <hip/hip_runtime.h>

#define NN 50000
#define F 128

// ---------------- dtype probe: int64 vs int32 edge_index ----------------
__global__ void detect_i64(const int* __restrict__ ei, int* __restrict__ flag) {
    __shared__ int any_nonzero;
    if (threadIdx.x == 0) any_nonzero = 0;
    __syncthreads();
    // If data is int64 (little-endian, values < 2^31), every odd 32-bit word is 0.
    int v = ei[2 * threadIdx.x + 1];
    if (v != 0) atomicOr(&any_nonzero, 1);
    __syncthreads();
    if (threadIdx.x == 0) *flag = (any_nonzero == 0) ? 1 : 0;  // 1 => int64
}

__device__ __forceinline__ int load_src(const int* ei, int is64, int E, int e) {
    return is64 ? ei[2 * e] : ei[e];
}
__device__ __forceinline__ int load_dst(const int* ei, int is64, int E, int e) {
    return is64 ? ei[2 * (E + e)] : ei[E + e];
}

// ---------------- degree count ----------------
__global__ void count_edges(const int* __restrict__ ei, const int* __restrict__ flag,
                            float* __restrict__ cnt, int E) {
    int i = blockIdx.x * blockDim.x + threadIdx.x;
    if (i >= E) return;
    int is64 = *flag;
    int d = load_dst(ei, is64, E, i);
    atomicAdd(&cnt[d], 1.0f);
}

// ---------------- scatter-sum: agg[dst] += x[src] ----------------
// one thread per (edge, 4 features): 32 threads per edge, float4 gather
__global__ void scatter_sum(const float* __restrict__ xin, const int* __restrict__ ei,
                            const int* __restrict__ flag, float* __restrict__ agg, int E) {
    int idx = blockIdx.x * blockDim.x + threadIdx.x;
    int e = idx >> 5;
    if (e >= E) return;
    int f4 = (idx & 31) << 2;
    int is64 = *flag;
    int s = load_src(ei, is64, E, e);
    int d = load_dst(ei, is64, E, e);
    const float4 v = *(const float4*)(xin + (size_t)s * F + f4);
    float* o = agg + (size_t)d * F + f4;
    atomicAdd(o + 0, v.x);
    atomicAdd(o + 1, v.y);
    atomicAdd(o + 2, v.z);
    atomicAdd(o + 3, v.w);
}

// ---------------- fused layer GEMM: out = (agg/cnt) @ Wl + bl + xin @ Wr ----------------
// block = 256 threads; 32 rows x 128 cols per block; k tiled by 32.
// j = tid & 127 (output col), half = tid >> 7 selects 16 of the 32 rows.
__global__ __launch_bounds__(256) void sage_layer(
    const float* __restrict__ xin, const float* __restrict__ agg,
    const float* __restrict__ cnt,
    const float* __restrict__ Wl, const float* __restrict__ bl,
    const float* __restrict__ Wr,
    float* __restrict__ out, int N, int relu) {
    __shared__ float sWl[32][128];
    __shared__ float sWr[32][128];
    __shared__ float sA[32][40];  // row stride 160B: float4-aligned
    __shared__ float sX[32][40];

    const int tid = threadIdx.x;
    const int j = tid & 127;
    const int half = tid >> 7;
    const int row0 = blockIdx.x * 32;

    float accA[16], accX[16];
#pragma unroll
    for (int r = 0; r < 16; ++r) { accA[r] = 0.f; accX[r] = 0.f; }

    for (int kt = 0; kt < 4; ++kt) {
        // stage W tiles (coalesced)
#pragma unroll
        for (int i = 0; i < 16; ++i) {
            int idx = tid + i * 256;
            int k = idx >> 7, jj = idx & 127;
            sWl[k][jj] = Wl[(kt * 32 + k) * F + jj];
            sWr[k][jj] = Wr[(kt * 32 + k) * F + jj];
        }
        // stage row tiles
#pragma unroll
        for (int i = 0; i < 4; ++i) {
            int idx = tid + i * 256;
            int r = idx >> 5, k = idx & 31;
            int row = row0 + r;
            float a = 0.f, xv = 0.f;
            if (row < N) {
                a = agg[(size_t)row * F + kt * 32 + k];
                xv = xin[(size_t)row * F + kt * 32 + k];
            }
            sA[r][k] = a;
            sX[r][k] = xv;
        }
        __syncthreads();

#pragma unroll
        for (int k4 = 0; k4 < 8; ++k4) {
            const int kb = k4 * 4;
            float wl0 = sWl[kb + 0][j], wl1 = sWl[kb + 1][j];
            float wl2 = sWl[kb + 2][j], wl3 = sWl[kb + 3][j];
            float wr0 = sWr[kb + 0][j], wr1 = sWr[kb + 1][j];
            float wr2 = sWr[kb + 2][j], wr3 = sWr[kb + 3][j];
#pragma unroll
            for (int r = 0; r < 16; ++r) {
                const float4 a = *(const float4*)&sA[half * 16 + r][kb];
                const float4 xv = *(const float4*)&sX[half * 16 + r][kb];
                accA[r] += a.x * wl0 + a.y * wl1 + a.z * wl2 + a.w * wl3;
                accX[r] += xv.x * wr0 + xv.y * wr1 + xv.z * wr2 + xv.w * wr3;
            }
        }
        __syncthreads();
    }

    const float b = bl[j];
#pragma unroll
    for (int r = 0; r < 16; ++r) {
        int row = row0 + half * 16 + r;
        if (row < N) {
            float inv = 1.0f / fmaxf(cnt[row], 1.0f);
            float v = accA[r] * inv + accX[r] + b;
            if (relu) v = fmaxf(v, 0.f);
            out[(size_t)row * F + j] = v;
        }
    }
}

extern "C" void kernel_launch(void* const* d_in, const int* in_sizes, int n_in,
                              void* d_out, int out_size, void* d_ws, size_t ws_size,
                              hipStream_t stream) {
    const float* x = (const float*)d_in[0];
    const int* ei = (const int*)d_in[1];
    const int E = in_sizes[1] / 2;
    const int N = in_sizes[0] / F;

    const float* Wl[3] = {(const float*)d_in[2], (const float*)d_in[5], (const float*)d_in[8]};
    const float* bl[3] = {(const float*)d_in[3], (const float*)d_in[6], (const float*)d_in[9]};
    const float* Wr[3] = {(const float*)d_in[4], (const float*)d_in[7], (const float*)d_in[10]};
    float* out = (float*)d_out;

    char* ws = (char*)d_ws;
    size_t off = 0;
    auto alloc = [&](size_t bytes) {
        size_t o = off;
        off = (off + bytes + 255) & ~(size_t)255;
        return o;
    };
    int* flag = (int*)(ws + alloc(4));
    float* cnt = (float*)(ws + alloc((size_t)N * 4));
    float* agg = (float*)(ws + alloc((size_t)N * F * 4));
    float* h1 = (float*)(ws + alloc((size_t)N * F * 4));
    float* h2 = (float*)(ws + alloc((size_t)N * F * 4));

    detect_i64<<<1, 256, 0, stream>>>(ei, flag);
    hipMemsetAsync(cnt, 0, (size_t)N * 4, stream);
    count_edges<<<(E + 255) / 256, 256, 0, stream>>>(ei, flag, cnt, E);

    const float* cur = x;
    float* outs[3] = {h1, h2, out};
    for (int layer = 0; layer < 3; ++layer) {
        hipMemsetAsync(agg, 0, (size_t)N * F * 4, stream);
        int scatter_threads = E * 32;
        scatter_sum<<<(scatter_threads + 255) / 256, 256, 0, stream>>>(cur, ei, flag, agg, E);
        sage_layer<<<(N + 31) / 32, 256, 0, stream>>>(cur, agg, cnt, Wl[layer], bl[layer],
                                                      Wr[layer], outs[layer], N, layer < 2);
        cur = outs[layer];
    }
}

// Round 2
// 1082.779 us; speedup vs baseline: 4.5821x; 4.5821x over previous
//
#include <hip/hip_runtime.h>

#define F 128

// ---------------- dtype probe: int64 vs int32 edge_index ----------------
__global__ void detect_i64(const int* __restrict__ ei, int* __restrict__ flag) {
    __shared__ int any_nonzero;
    if (threadIdx.x == 0) any_nonzero = 0;
    __syncthreads();
    // If data is int64 (little-endian, values < 2^31), every odd 32-bit word is 0.
    int v = ei[2 * threadIdx.x + 1];
    if (v != 0) atomicOr(&any_nonzero, 1);
    __syncthreads();
    if (threadIdx.x == 0) *flag = (any_nonzero == 0) ? 1 : 0;  // 1 => int64
}

__device__ __forceinline__ int load_src(const int* ei, int is64, int E, int e) {
    return is64 ? ei[2 * e] : ei[e];
}
__device__ __forceinline__ int load_dst(const int* ei, int is64, int E, int e) {
    return is64 ? ei[2 * (E + e)] : ei[E + e];
}

// ---------------- degree histogram (int atomics) ----------------
__global__ void count_edges(const int* __restrict__ ei, const int* __restrict__ flag,
                            int* __restrict__ deg, int E) {
    int i = blockIdx.x * blockDim.x + threadIdx.x;
    if (i >= E) return;
    int is64 = *flag;
    atomicAdd(&deg[load_dst(ei, is64, E, i)], 1);
}

// ---------------- single-block exclusive scan of degrees ----------------
__global__ __launch_bounds__(1024) void scan_deg(const int* __restrict__ deg,
                                                 int* __restrict__ rs, int N) {
    __shared__ int wsum[16];
    __shared__ int chunk_total;
    const int tid = threadIdx.x;
    const int lane = tid & 63, wid = tid >> 6;
    int running = 0;
    for (int base = 0; base < N; base += 1024) {
        int i = base + tid;
        int v = (i < N) ? deg[i] : 0;
        int incl = v;
#pragma unroll
        for (int d = 1; d < 64; d <<= 1) {
            int t = __shfl_up(incl, d);
            if (lane >= d) incl += t;
        }
        if (lane == 63) wsum[wid] = incl;
        __syncthreads();
        if (tid == 0) {
            int acc = 0;
#pragma unroll
            for (int w = 0; w < 16; ++w) { int t = wsum[w]; wsum[w] = acc; acc += t; }
            chunk_total = acc;
        }
        __syncthreads();
        if (i < N) rs[i] = running + wsum[wid] + (incl - v);
        running += chunk_total;
        __syncthreads();  // protect wsum before next iteration overwrites
    }
}

// ---------------- CSR fill: adj[rs[dst] + rank] = src ----------------
__global__ void fill_adj(const int* __restrict__ ei, const int* __restrict__ flag,
                         const int* __restrict__ rs, int* __restrict__ fillpos,
                         int* __restrict__ adj, int E) {
    int e = blockIdx.x * blockDim.x + threadIdx.x;
    if (e >= E) return;
    int is64 = *flag;
    int s = load_src(ei, is64, E, e);
    int d = load_dst(ei, is64, E, e);
    int r = atomicAdd(&fillpos[d], 1);
    adj[rs[d] + r] = s;
}

// ---------------- gather-mean: agg[n] = mean_{s in adj[n]} x[s] ----------------
// one wave (64 lanes) per node; each lane owns 2 features (float2)
__global__ __launch_bounds__(256) void gather_mean(
    const float* __restrict__ xin, const int* __restrict__ adj,
    const int* __restrict__ rs, const int* __restrict__ deg,
    float* __restrict__ agg, int N) {
    int n = (blockIdx.x * blockDim.x + threadIdx.x) >> 6;
    if (n >= N) return;
    const int lane = threadIdx.x & 63;
    const int start = rs[n];
    const int d = deg[n];
    float ax = 0.f, ay = 0.f;
    int i = 0;
    // unroll-4 so 4 gathers are in flight
    for (; i + 4 <= d; i += 4) {
        int s0 = adj[start + i + 0];
        int s1 = adj[start + i + 1];
        int s2 = adj[start + i + 2];
        int s3 = adj[start + i + 3];
        float2 v0 = *(const float2*)(xin + (size_t)s0 * F + lane * 2);
        float2 v1 = *(const float2*)(xin + (size_t)s1 * F + lane * 2);
        float2 v2 = *(const float2*)(xin + (size_t)s2 * F + lane * 2);
        float2 v3 = *(const float2*)(xin + (size_t)s3 * F + lane * 2);
        ax += v0.x + v1.x + v2.x + v3.x;
        ay += v0.y + v1.y + v2.y + v3.y;
    }
    for (; i < d; ++i) {
        int s = adj[start + i];
        float2 v = *(const float2*)(xin + (size_t)s * F + lane * 2);
        ax += v.x;
        ay += v.y;
    }
    float inv = 1.0f / fmaxf((float)d, 1.0f);
    float2 o;
    o.x = ax * inv;
    o.y = ay * inv;
    *(float2*)(agg + (size_t)n * F + lane * 2) = o;
}

// ---------------- fused layer GEMM: out = agg @ Wl + bl + xin @ Wr ----------------
// block = 256 threads; 32 rows x 128 cols per block; k tiled by 32.
__global__ __launch_bounds__(256) void sage_layer(
    const float* __restrict__ xin, const float* __restrict__ agg,
    const float* __restrict__ Wl, const float* __restrict__ bl,
    const float* __restrict__ Wr,
    float* __restrict__ out, int N, int relu) {
    __shared__ float sWl[32][128];
    __shared__ float sWr[32][128];
    __shared__ float sA[32][40];  // row stride 160B: float4-aligned
    __shared__ float sX[32][40];

    const int tid = threadIdx.x;
    const int j = tid & 127;
    const int half = tid >> 7;
    const int row0 = blockIdx.x * 32;

    float accA[16], accX[16];
#pragma unroll
    for (int r = 0; r < 16; ++r) { accA[r] = 0.f; accX[r] = 0.f; }

    for (int kt = 0; kt < 4; ++kt) {
#pragma unroll
        for (int i = 0; i < 16; ++i) {
            int idx = tid + i * 256;
            int k = idx >> 7, jj = idx & 127;
            sWl[k][jj] = Wl[(kt * 32 + k) * F + jj];
            sWr[k][jj] = Wr[(kt * 32 + k) * F + jj];
        }
#pragma unroll
        for (int i = 0; i < 4; ++i) {
            int idx = tid + i * 256;
            int r = idx >> 5, k = idx & 31;
            int row = row0 + r;
            float a = 0.f, xv = 0.f;
            if (row < N) {
                a = agg[(size_t)row * F + kt * 32 + k];
                xv = xin[(size_t)row * F + kt * 32 + k];
            }
            sA[r][k] = a;
            sX[r][k] = xv;
        }
        __syncthreads();

#pragma unroll
        for (int k4 = 0; k4 < 8; ++k4) {
            const int kb = k4 * 4;
            float wl0 = sWl[kb + 0][j], wl1 = sWl[kb + 1][j];
            float wl2 = sWl[kb + 2][j], wl3 = sWl[kb + 3][j];
            float wr0 = sWr[kb + 0][j], wr1 = sWr[kb + 1][j];
            float wr2 = sWr[kb + 2][j], wr3 = sWr[kb + 3][j];
#pragma unroll
            for (int r = 0; r < 16; ++r) {
                const float4 a = *(const float4*)&sA[half * 16 + r][kb];
                const float4 xv = *(const float4*)&sX[half * 16 + r][kb];
                accA[r] += a.x * wl0 + a.y * wl1 + a.z * wl2 + a.w * wl3;
                accX[r] += xv.x * wr0 + xv.y * wr1 + xv.z * wr2 + xv.w * wr3;
            }
        }
        __syncthreads();
    }

    const float b = bl[j];
#pragma unroll
    for (int r = 0; r < 16; ++r) {
        int row = row0 + half * 16 + r;
        if (row < N) {
            float v = accA[r] + accX[r] + b;
            if (relu) v = fmaxf(v, 0.f);
            out[(size_t)row * F + j] = v;
        }
    }
}

extern "C" void kernel_launch(void* const* d_in, const int* in_sizes, int n_in,
                              void* d_out, int out_size, void* d_ws, size_t ws_size,
                              hipStream_t stream) {
    const float* x = (const float*)d_in[0];
    const int* ei = (const int*)d_in[1];
    const int E = in_sizes[1] / 2;
    const int N = in_sizes[0] / F;

    const float* Wl[3] = {(const float*)d_in[2], (const float*)d_in[5], (const float*)d_in[8]};
    const float* bl[3] = {(const float*)d_in[3], (const float*)d_in[6], (const float*)d_in[9]};
    const float* Wr[3] = {(const float*)d_in[4], (const float*)d_in[7], (const float*)d_in[10]};
    float* out = (float*)d_out;

    char* ws = (char*)d_ws;
    size_t off = 0;
    auto alloc = [&](size_t bytes) {
        size_t o = off;
        off = (off + bytes + 255) & ~(size_t)255;
        return o;
    };
    int* flag = (int*)(ws + alloc(4));
    int* deg = (int*)(ws + alloc((size_t)N * 4));
    int* rs = (int*)(ws + alloc((size_t)N * 4));
    int* fillpos = (int*)(ws + alloc((size_t)N * 4));
    int* adj = (int*)(ws + alloc((size_t)E * 4));
    float* agg = (float*)(ws + alloc((size_t)N * F * 4));
    float* h1 = (float*)(ws + alloc((size_t)N * F * 4));
    float* h2 = (float*)(ws + alloc((size_t)N * F * 4));

    // ---- CSR build (once; reused by all 3 layers) ----
    detect_i64<<<1, 256, 0, stream>>>(ei, flag);
    hipMemsetAsync(deg, 0, (size_t)N * 4, stream);
    hipMemsetAsync(fillpos, 0, (size_t)N * 4, stream);
    count_edges<<<(E + 255) / 256, 256, 0, stream>>>(ei, flag, deg, E);
    scan_deg<<<1, 1024, 0, stream>>>(deg, rs, N);
    fill_adj<<<(E + 255) / 256, 256, 0, stream>>>(ei, flag, rs, fillpos, adj, E);

    const float* cur = x;
    float* outs[3] = {h1, h2, out};
    for (int layer = 0; layer < 3; ++layer) {
        int waves = N;  // one wave per node
        gather_mean<<<(waves * 64 + 255) / 256, 256, 0, stream>>>(cur, adj, rs, deg, agg, N);
        sage_layer<<<(N + 31) / 32, 256, 0, stream>>>(cur, agg, Wl[layer], bl[layer],
                                                      Wr[layer], outs[layer], N, layer < 2);
        cur = outs[layer];
    }
}

// Round 3
// 311.629 us; speedup vs baseline: 15.9207x; 3.4746x over previous
//
#include <hip/hip_runtime.h>

#define F 128

typedef __attribute__((ext_vector_type(8))) short short8v;   // 8 bf16 (4 VGPR)
typedef __attribute__((ext_vector_type(4))) float f32x4;     // MFMA accumulator

__device__ __forceinline__ unsigned short f2bf(float f) {
    unsigned int u = __builtin_bit_cast(unsigned int, f);
    unsigned int r = (u + 0x7fffu + ((u >> 16) & 1u)) >> 16;
    return (unsigned short)r;
}
__device__ __forceinline__ float bf2f(unsigned short b) {
    unsigned int u = ((unsigned int)b) << 16;
    return __builtin_bit_cast(float, u);
}

// ---------------- dtype probe: int64 vs int32 edge_index ----------------
__global__ void detect_i64(const int* __restrict__ ei, int* __restrict__ flag) {
    __shared__ int any_nonzero;
    if (threadIdx.x == 0) any_nonzero = 0;
    __syncthreads();
    int v = ei[2 * threadIdx.x + 1];
    if (v != 0) atomicOr(&any_nonzero, 1);
    __syncthreads();
    if (threadIdx.x == 0) *flag = (any_nonzero == 0) ? 1 : 0;  // 1 => int64
}

__device__ __forceinline__ int load_src(const int* ei, int is64, int E, int e) {
    return is64 ? ei[2 * e] : ei[e];
}
__device__ __forceinline__ int load_dst(const int* ei, int is64, int E, int e) {
    return is64 ? ei[2 * (E + e)] : ei[E + e];
}

// ---------------- degree histogram ----------------
__global__ void count_edges(const int* __restrict__ ei, const int* __restrict__ flag,
                            int* __restrict__ deg, int E) {
    int i = blockIdx.x * blockDim.x + threadIdx.x;
    if (i >= E) return;
    int is64 = *flag;
    atomicAdd(&deg[load_dst(ei, is64, E, i)], 1);
}

// ---------------- single-block exclusive scan of degrees ----------------
__global__ __launch_bounds__(1024) void scan_deg(const int* __restrict__ deg,
                                                 int* __restrict__ rs, int N) {
    __shared__ int wsum[16];
    __shared__ int chunk_total;
    const int tid = threadIdx.x;
    const int lane = tid & 63, wid = tid >> 6;
    int running = 0;
    for (int base = 0; base < N; base += 1024) {
        int i = base + tid;
        int v = (i < N) ? deg[i] : 0;
        int incl = v;
#pragma unroll
        for (int d = 1; d < 64; d <<= 1) {
            int t = __shfl_up(incl, d);
            if (lane >= d) incl += t;
        }
        if (lane == 63) wsum[wid] = incl;
        __syncthreads();
        if (tid == 0) {
            int acc = 0;
#pragma unroll
            for (int w = 0; w < 16; ++w) { int t = wsum[w]; wsum[w] = acc; acc += t; }
            chunk_total = acc;
        }
        __syncthreads();
        if (i < N) rs[i] = running + wsum[wid] + (incl - v);
        running += chunk_total;
        __syncthreads();
    }
}

// ---------------- CSR fill ----------------
__global__ void fill_adj(const int* __restrict__ ei, const int* __restrict__ flag,
                         const int* __restrict__ rs, int* __restrict__ fillpos,
                         int* __restrict__ adj, int E) {
    int e = blockIdx.x * blockDim.x + threadIdx.x;
    if (e >= E) return;
    int is64 = *flag;
    int s = load_src(ei, is64, E, e);
    int d = load_dst(ei, is64, E, e);
    int r = atomicAdd(&fillpos[d], 1);
    adj[rs[d] + r] = s;
}

// ---------------- x fp32 -> bf16 ----------------
__global__ void convert_x(const float* __restrict__ x, unsigned short* __restrict__ xb,
                          int total) {
    int i = blockIdx.x * blockDim.x + threadIdx.x;
    if (i * 4 >= total) return;
    float4 v = *(const float4*)(x + i * 4);
    ushort4 o;
    o.x = f2bf(v.x); o.y = f2bf(v.y); o.z = f2bf(v.z); o.w = f2bf(v.w);
    *(ushort4*)(xb + i * 4) = o;
}

// ---------------- pack [Wl;Wr] (256x128) into MFMA B-fragment layout ----------------
// Wpack[L][kt][nt][lane][i] = W[kt*32 + (lane>>4)*8 + i][nt*16 + (lane&15)]
__global__ void convert_w(const float* __restrict__ Wl, const float* __restrict__ Wr,
                          unsigned short* __restrict__ Wpack) {
    int t = blockIdx.x * blockDim.x + threadIdx.x;  // (kt*8+nt)*64 + lane, 4096 total
    if (t >= 4096) return;
    int lane = t & 63;
    int nt = (t >> 6) & 7;
    int kt = (t >> 9) & 7;
    int c = nt * 16 + (lane & 15);
    int kbase = kt * 32 + ((lane >> 4) << 3);
    unsigned short o[8];
#pragma unroll
    for (int i = 0; i < 8; ++i) {
        int k = kbase + i;
        float v = (k < 128) ? Wl[k * F + c] : Wr[(k - 128) * F + c];
        o[i] = f2bf(v);
    }
    *(uint4*)(Wpack + (size_t)t * 8) = *(const uint4*)o;
}

// ---------------- gather-mean (bf16 in/out, fp32 accumulate) ----------------
// one wave per node; lane owns 2 features (one dword)
__global__ __launch_bounds__(256) void gather_mean(
    const unsigned short* __restrict__ xb, const int* __restrict__ adj,
    const int* __restrict__ rs, const int* __restrict__ deg,
    unsigned short* __restrict__ aggb, int N) {
    int n = (blockIdx.x * blockDim.x + threadIdx.x) >> 6;
    if (n >= N) return;
    const int lane = threadIdx.x & 63;
    const int start = rs[n];
    const int d = deg[n];
    float ax = 0.f, ay = 0.f;
    int i = 0;
    for (; i + 4 <= d; i += 4) {
        int s0 = adj[start + i + 0];
        int s1 = adj[start + i + 1];
        int s2 = adj[start + i + 2];
        int s3 = adj[start + i + 3];
        unsigned int v0 = *(const unsigned int*)(xb + (size_t)s0 * F + lane * 2);
        unsigned int v1 = *(const unsigned int*)(xb + (size_t)s1 * F + lane * 2);
        unsigned int v2 = *(const unsigned int*)(xb + (size_t)s2 * F + lane * 2);
        unsigned int v3 = *(const unsigned int*)(xb + (size_t)s3 * F + lane * 2);
        ax += bf2f(v0 & 0xffff) + bf2f(v1 & 0xffff) + bf2f(v2 & 0xffff) + bf2f(v3 & 0xffff);
        ay += bf2f(v0 >> 16) + bf2f(v1 >> 16) + bf2f(v2 >> 16) + bf2f(v3 >> 16);
    }
    for (; i < d; ++i) {
        int s = adj[start + i];
        unsigned int v = *(const unsigned int*)(xb + (size_t)s * F + lane * 2);
        ax += bf2f(v & 0xffff);
        ay += bf2f(v >> 16);
    }
    float inv = 1.0f / fmaxf((float)d, 1.0f);
    unsigned int o = ((unsigned int)f2bf(ay * inv) << 16) | f2bf(ax * inv);
    *(unsigned int*)(aggb + (size_t)n * F + lane * 2) = o;
}

// ---------------- MFMA layer: out = [agg|x] @ Wpack + bl (+relu) ----------------
// 4 waves/block, each wave: 16 rows x 128 cols, K=256 (8 ktiles of 32)
__global__ __launch_bounds__(256) void sage_mfma(
    const unsigned short* __restrict__ aggb, const unsigned short* __restrict__ xb,
    const unsigned short* __restrict__ Wpack, const float* __restrict__ bl,
    unsigned short* __restrict__ outb, float* __restrict__ outf,
    int N, int final_layer) {
    const int wid = threadIdx.x >> 6;
    const int lane = threadIdx.x & 63;
    const int gw = blockIdx.x * 4 + wid;
    const int row0 = gw * 16;
    if (row0 >= N) return;

    const int rA = row0 + (lane & 15);
    const int kidx = (lane >> 4) << 3;  // 0,8,16,24

    f32x4 acc[8];
#pragma unroll
    for (int nt = 0; nt < 8; ++nt) acc[nt] = (f32x4){0.f, 0.f, 0.f, 0.f};

    const unsigned short* arow_a = aggb + (size_t)rA * F + kidx;
    const unsigned short* arow_x = xb + (size_t)rA * F + kidx;

#pragma unroll
    for (int kt = 0; kt < 8; ++kt) {
        const unsigned short* ap = (kt < 4) ? (arow_a + kt * 32) : (arow_x + (kt - 4) * 32);
        short8v a = *(const short8v*)ap;
#pragma unroll
        for (int nt = 0; nt < 8; ++nt) {
            short8v b = *(const short8v*)(Wpack + ((size_t)(kt * 8 + nt) * 64 + lane) * 8);
            acc[nt] = __builtin_amdgcn_mfma_f32_16x16x32_bf16(a, b, acc[nt], 0, 0, 0);
        }
    }

    // C/D layout: col = lane&15, row = (lane>>4)*4 + reg   [m89-verified]
    const int c0 = lane & 15;
    const int r0 = row0 + ((lane >> 4) << 2);
#pragma unroll
    for (int nt = 0; nt < 8; ++nt) {
        const int col = nt * 16 + c0;
        const float b = bl[col];
#pragma unroll
        for (int reg = 0; reg < 4; ++reg) {
            const int r = r0 + reg;
            float v = acc[nt][reg] + b;
            if (!final_layer) {
                v = fmaxf(v, 0.f);
                outb[(size_t)r * F + col] = f2bf(v);
            } else {
                outf[(size_t)r * F + col] = v;
            }
        }
    }
}

extern "C" void kernel_launch(void* const* d_in, const int* in_sizes, int n_in,
                              void* d_out, int out_size, void* d_ws, size_t ws_size,
                              hipStream_t stream) {
    const float* x = (const float*)d_in[0];
    const int* ei = (const int*)d_in[1];
    const int E = in_sizes[1] / 2;
    const int N = in_sizes[0] / F;

    const float* Wl[3] = {(const float*)d_in[2], (const float*)d_in[5], (const float*)d_in[8]};
    const float* bl[3] = {(const float*)d_in[3], (const float*)d_in[6], (const float*)d_in[9]};
    const float* Wr[3] = {(const float*)d_in[4], (const float*)d_in[7], (const float*)d_in[10]};
    float* out = (float*)d_out;

    char* ws = (char*)d_ws;
    size_t off = 0;
    auto alloc = [&](size_t bytes) {
        size_t o = off;
        off = (off + bytes + 255) & ~(size_t)255;
        return o;
    };
    int* flag = (int*)(ws + alloc(4));
    int* deg = (int*)(ws + alloc((size_t)N * 4));
    int* rs = (int*)(ws + alloc((size_t)N * 4));
    int* fillpos = (int*)(ws + alloc((size_t)N * 4));
    int* adj = (int*)(ws + alloc((size_t)E * 4));
    unsigned short* xb = (unsigned short*)(ws + alloc((size_t)N * F * 2));
    unsigned short* aggb = (unsigned short*)(ws + alloc((size_t)N * F * 2));
    unsigned short* h1b = (unsigned short*)(ws + alloc((size_t)N * F * 2));
    unsigned short* h2b = (unsigned short*)(ws + alloc((size_t)N * F * 2));
    unsigned short* Wp = (unsigned short*)(ws + alloc((size_t)3 * 4096 * 8 * 2));

    // ---- CSR build (once) ----
    detect_i64<<<1, 256, 0, stream>>>(ei, flag);
    hipMemsetAsync(deg, 0, (size_t)N * 4, stream);
    hipMemsetAsync(fillpos, 0, (size_t)N * 4, stream);
    count_edges<<<(E + 255) / 256, 256, 0, stream>>>(ei, flag, deg, E);
    scan_deg<<<1, 1024, 0, stream>>>(deg, rs, N);
    fill_adj<<<(E + 255) / 256, 256, 0, stream>>>(ei, flag, rs, fillpos, adj, E);

    // ---- conversions ----
    convert_x<<<((N * F / 4) + 255) / 256, 256, 0, stream>>>(x, xb, N * F);
    for (int L = 0; L < 3; ++L)
        convert_w<<<16, 256, 0, stream>>>(Wl[L], Wr[L], Wp + (size_t)L * 32768);

    // ---- layers ----
    const unsigned short* cur = xb;
    unsigned short* hb[3] = {h1b, h2b, nullptr};
    int nblocks = ((N + 15) / 16 + 3) / 4;
    for (int layer = 0; layer < 3; ++layer) {
        gather_mean<<<(N * 64 + 255) / 256, 256, 0, stream>>>(cur, adj, rs, deg, aggb, N);
        sage_mfma<<<nblocks, 256, 0, stream>>>(aggb, cur, Wp + (size_t)layer * 32768,
                                               bl[layer], hb[layer], out, N, layer == 2);
        cur = hb[layer];
    }
}

// Round 4
// 225.032 us; speedup vs baseline: 22.0474x; 1.3848x over previous
//
#include <hip/hip_runtime.h>

#define F 128

typedef __attribute__((ext_vector_type(8))) short short8v;   // 8 bf16 (4 VGPR)
typedef __attribute__((ext_vector_type(4))) float f32x4;     // MFMA accumulator

__device__ __forceinline__ unsigned short f2bf(float f) {
    unsigned int u = __builtin_bit_cast(unsigned int, f);
    unsigned int r = (u + 0x7fffu + ((u >> 16) & 1u)) >> 16;
    return (unsigned short)r;
}
__device__ __forceinline__ float bf2f(unsigned int b16) {
    unsigned int u = b16 << 16;
    return __builtin_bit_cast(float, u);
}

// ---------------- dtype probe: int64 vs int32 edge_index ----------------
__global__ void detect_i64(const int* __restrict__ ei, int* __restrict__ flag) {
    __shared__ int any_nonzero;
    if (threadIdx.x == 0) any_nonzero = 0;
    __syncthreads();
    int v = ei[2 * threadIdx.x + 1];
    if (v != 0) atomicOr(&any_nonzero, 1);
    __syncthreads();
    if (threadIdx.x == 0) *flag = (any_nonzero == 0) ? 1 : 0;  // 1 => int64
}

__device__ __forceinline__ int load_src(const int* ei, int is64, int E, int e) {
    return is64 ? ei[2 * e] : ei[e];
}
__device__ __forceinline__ int load_dst(const int* ei, int is64, int E, int e) {
    return is64 ? ei[2 * (E + e)] : ei[E + e];
}

// ---------------- degree histogram + per-edge rank ----------------
__global__ void count_rank(const int* __restrict__ ei, const int* __restrict__ flag,
                           int* __restrict__ deg, int* __restrict__ rank, int E) {
    int e = blockIdx.x * blockDim.x + threadIdx.x;
    if (e >= E) return;
    int is64 = *flag;
    int d = load_dst(ei, is64, E, e);
    rank[e] = atomicAdd(&deg[d], 1);
}

// ---------------- 2-level scan: local chunks of 1024 ----------------
__global__ __launch_bounds__(1024) void scan_local(const int* __restrict__ deg,
                                                   int* __restrict__ rs,
                                                   int* __restrict__ partials, int N) {
    __shared__ int wsum[16];
    const int tid = threadIdx.x;
    const int lane = tid & 63, wid = tid >> 6;
    int i = blockIdx.x * 1024 + tid;
    int v = (i < N) ? deg[i] : 0;
    int incl = v;
#pragma unroll
    for (int d = 1; d < 64; d <<= 1) {
        int t = __shfl_up(incl, d);
        if (lane >= d) incl += t;
    }
    if (lane == 63) wsum[wid] = incl;
    __syncthreads();
    if (tid == 0) {
        int acc = 0;
#pragma unroll
        for (int w = 0; w < 16; ++w) { int t = wsum[w]; wsum[w] = acc; acc += t; }
        partials[blockIdx.x] = acc;
    }
    __syncthreads();
    if (i < N) rs[i] = wsum[wid] + (incl - v);  // chunk-local exclusive prefix
}

// scan the <=64 chunk totals with one wave -> chunk offsets
__global__ void scan_part(const int* __restrict__ partials, int* __restrict__ coff,
                          int nch) {
    int tid = threadIdx.x;
    int v = (tid < nch) ? partials[tid] : 0;
    int incl = v;
#pragma unroll
    for (int d = 1; d < 64; d <<= 1) {
        int t = __shfl_up(incl, d);
        if (tid >= d) incl += t;
    }
    coff[tid] = incl - v;  // exclusive
}

// ---------------- CSR fill (atomic-free) ----------------
__global__ void fill_adj(const int* __restrict__ ei, const int* __restrict__ flag,
                         const int* __restrict__ rs, const int* __restrict__ coff,
                         const int* __restrict__ rank, int* __restrict__ adj, int E) {
    int e = blockIdx.x * blockDim.x + threadIdx.x;
    if (e >= E) return;
    int is64 = *flag;
    int s = load_src(ei, is64, E, e);
    int d = load_dst(ei, is64, E, e);
    adj[rs[d] + coff[d >> 10] + rank[e]] = s;
}

// ---------------- x fp32 -> bf16 ----------------
__global__ void convert_x(const float* __restrict__ x, unsigned short* __restrict__ xb,
                          int total) {
    int i = blockIdx.x * blockDim.x + threadIdx.x;
    if (i * 4 >= total) return;
    float4 v = *(const float4*)(x + i * 4);
    ushort4 o;
    o.x = f2bf(v.x); o.y = f2bf(v.y); o.z = f2bf(v.z); o.w = f2bf(v.w);
    *(ushort4*)(xb + i * 4) = o;
}

// ---------------- pack [Wl;Wr] (256x128) into MFMA B-fragment layout ----------------
__global__ void convert_w(const float* __restrict__ Wl, const float* __restrict__ Wr,
                          unsigned short* __restrict__ Wpack) {
    int t = blockIdx.x * blockDim.x + threadIdx.x;  // (kt*8+nt)*64 + lane, 4096 total
    if (t >= 4096) return;
    int lane = t & 63;
    int nt = (t >> 6) & 7;
    int kt = (t >> 9) & 7;
    int c = nt * 16 + (lane & 15);
    int kbase = kt * 32 + ((lane >> 4) << 3);
    unsigned short o[8];
#pragma unroll
    for (int i = 0; i < 8; ++i) {
        int k = kbase + i;
        float v = (k < 128) ? Wl[k * F + c] : Wr[(k - 128) * F + c];
        o[i] = f2bf(v);
    }
    *(uint4*)(Wpack + (size_t)t * 8) = *(const uint4*)o;
}

// ---------------- gather-mean: 2 edges per wave-issue ----------------
// one wave per node; lanes 0-31 = even-offset edges, lanes 32-63 = odd; lane owns 4 feats (8B)
__global__ __launch_bounds__(256) void gather_mean(
    const unsigned short* __restrict__ xb, const int* __restrict__ adj,
    const int* __restrict__ rs, const int* __restrict__ coff,
    const int* __restrict__ deg, unsigned short* __restrict__ aggb, int N) {
    int n = (blockIdx.x * blockDim.x + threadIdx.x) >> 6;
    if (n >= N) return;
    const int lane = threadIdx.x & 63;
    const int half = lane >> 5, l5 = lane & 31;
    const int start = rs[n] + coff[n >> 10];
    const int d = deg[n];
    float a0 = 0.f, a1 = 0.f, a2 = 0.f, a3 = 0.f;
    int i = half;
    for (; i + 6 < d; i += 8) {
        int s0 = adj[start + i + 0];
        int s1 = adj[start + i + 2];
        int s2 = adj[start + i + 4];
        int s3 = adj[start + i + 6];
        uint2 v0 = *(const uint2*)(xb + (size_t)s0 * F + l5 * 4);
        uint2 v1 = *(const uint2*)(xb + (size_t)s1 * F + l5 * 4);
        uint2 v2 = *(const uint2*)(xb + (size_t)s2 * F + l5 * 4);
        uint2 v3 = *(const uint2*)(xb + (size_t)s3 * F + l5 * 4);
        a0 += bf2f(v0.x & 0xffff) + bf2f(v1.x & 0xffff) + bf2f(v2.x & 0xffff) + bf2f(v3.x & 0xffff);
        a1 += bf2f(v0.x >> 16) + bf2f(v1.x >> 16) + bf2f(v2.x >> 16) + bf2f(v3.x >> 16);
        a2 += bf2f(v0.y & 0xffff) + bf2f(v1.y & 0xffff) + bf2f(v2.y & 0xffff) + bf2f(v3.y & 0xffff);
        a3 += bf2f(v0.y >> 16) + bf2f(v1.y >> 16) + bf2f(v2.y >> 16) + bf2f(v3.y >> 16);
    }
    for (; i < d; i += 2) {
        int s = adj[start + i];
        uint2 v = *(const uint2*)(xb + (size_t)s * F + l5 * 4);
        a0 += bf2f(v.x & 0xffff);
        a1 += bf2f(v.x >> 16);
        a2 += bf2f(v.y & 0xffff);
        a3 += bf2f(v.y >> 16);
    }
    // combine the two halves (lane ^ 32)
    a0 += __shfl_xor(a0, 32);
    a1 += __shfl_xor(a1, 32);
    a2 += __shfl_xor(a2, 32);
    a3 += __shfl_xor(a3, 32);
    if (half == 0) {
        float inv = 1.0f / fmaxf((float)d, 1.0f);
        uint2 o;
        o.x = ((unsigned int)f2bf(a1 * inv) << 16) | f2bf(a0 * inv);
        o.y = ((unsigned int)f2bf(a3 * inv) << 16) | f2bf(a2 * inv);
        *(uint2*)(aggb + (size_t)n * F + l5 * 4) = o;
    }
}

// ---------------- MFMA layer: out = [agg|x] @ Wpack + bl (+relu) ----------------
// 4 waves/block, each wave: 16 rows x 128 cols, K=256 (8 ktiles of 32)
__global__ __launch_bounds__(256) void sage_mfma(
    const unsigned short* __restrict__ aggb, const unsigned short* __restrict__ xb,
    const unsigned short* __restrict__ Wpack, const float* __restrict__ bl,
    unsigned short* __restrict__ outb, float* __restrict__ outf,
    int N, int final_layer) {
    const int wid = threadIdx.x >> 6;
    const int lane = threadIdx.x & 63;
    const int gw = blockIdx.x * 4 + wid;
    const int row0 = gw * 16;
    if (row0 >= N) return;

    const int rA = row0 + (lane & 15);
    const int kidx = (lane >> 4) << 3;  // 0,8,16,24

    f32x4 acc[8];
#pragma unroll
    for (int nt = 0; nt < 8; ++nt) acc[nt] = (f32x4){0.f, 0.f, 0.f, 0.f};

    const unsigned short* arow_a = aggb + (size_t)rA * F + kidx;
    const unsigned short* arow_x = xb + (size_t)rA * F + kidx;

#pragma unroll
    for (int kt = 0; kt < 8; ++kt) {
        const unsigned short* ap = (kt < 4) ? (arow_a + kt * 32) : (arow_x + (kt - 4) * 32);
        short8v a = *(const short8v*)ap;
#pragma unroll
        for (int nt = 0; nt < 8; ++nt) {
            short8v b = *(const short8v*)(Wpack + ((size_t)(kt * 8 + nt) * 64 + lane) * 8);
            acc[nt] = __builtin_amdgcn_mfma_f32_16x16x32_bf16(a, b, acc[nt], 0, 0, 0);
        }
    }

    // C/D layout: col = lane&15, row = (lane>>4)*4 + reg   [m89-verified]
    const int c0 = lane & 15;
    const int r0 = row0 + ((lane >> 4) << 2);
#pragma unroll
    for (int nt = 0; nt < 8; ++nt) {
        const int col = nt * 16 + c0;
        const float b = bl[col];
#pragma unroll
        for (int reg = 0; reg < 4; ++reg) {
            const int r = r0 + reg;
            float v = acc[nt][reg] + b;
            if (!final_layer) {
                v = fmaxf(v, 0.f);
                outb[(size_t)r * F + col] = f2bf(v);
            } else {
                outf[(size_t)r * F + col] = v;
            }
        }
    }
}

extern "C" void kernel_launch(void* const* d_in, const int* in_sizes, int n_in,
                              void* d_out, int out_size, void* d_ws, size_t ws_size,
                              hipStream_t stream) {
    const float* x = (const float*)d_in[0];
    const int* ei = (const int*)d_in[1];
    const int E = in_sizes[1] / 2;
    const int N = in_sizes[0] / F;
    const int NCH = (N + 1023) / 1024;

    const float* Wl[3] = {(const float*)d_in[2], (const float*)d_in[5], (const float*)d_in[8]};
    const float* bl[3] = {(const float*)d_in[3], (const float*)d_in[6], (const float*)d_in[9]};
    const float* Wr[3] = {(const float*)d_in[4], (const float*)d_in[7], (const float*)d_in[10]};
    float* out = (float*)d_out;

    char* ws = (char*)d_ws;
    size_t off = 0;
    auto alloc = [&](size_t bytes) {
        size_t o = off;
        off = (off + bytes + 255) & ~(size_t)255;
        return o;
    };
    int* flag = (int*)(ws + alloc(4));
    int* deg = (int*)(ws + alloc((size_t)N * 4));
    int* rs = (int*)(ws + alloc((size_t)N * 4));
    int* partials = (int*)(ws + alloc(64 * 4));
    int* coff = (int*)(ws + alloc(64 * 4));
    int* rank = (int*)(ws + alloc((size_t)E * 4));
    int* adj = (int*)(ws + alloc((size_t)E * 4));
    unsigned short* xb = (unsigned short*)(ws + alloc((size_t)N * F * 2));
    unsigned short* aggb = (unsigned short*)(ws + alloc((size_t)N * F * 2));
    unsigned short* h1b = (unsigned short*)(ws + alloc((size_t)N * F * 2));
    unsigned short* h2b = (unsigned short*)(ws + alloc((size_t)N * F * 2));
    unsigned short* Wp = (unsigned short*)(ws + alloc((size_t)3 * 4096 * 8 * 2));

    // ---- CSR build (once) ----
    detect_i64<<<1, 256, 0, stream>>>(ei, flag);
    hipMemsetAsync(deg, 0, (size_t)N * 4, stream);
    count_rank<<<(E + 255) / 256, 256, 0, stream>>>(ei, flag, deg, rank, E);
    scan_local<<<NCH, 1024, 0, stream>>>(deg, rs, partials, N);
    scan_part<<<1, 64, 0, stream>>>(partials, coff, NCH);
    fill_adj<<<(E + 255) / 256, 256, 0, stream>>>(ei, flag, rs, coff, rank, adj, E);

    // ---- conversions ----
    convert_x<<<((N * F / 4) + 255) / 256, 256, 0, stream>>>(x, xb, N * F);
    for (int L = 0; L < 3; ++L)
        convert_w<<<16, 256, 0, stream>>>(Wl[L], Wr[L], Wp + (size_t)L * 32768);

    // ---- layers ----
    const unsigned short* cur = xb;
    unsigned short* hb[3] = {h1b, h2b, nullptr};
    int nblocks = ((N + 15) / 16 + 3) / 4;
    for (int layer = 0; layer < 3; ++layer) {
        gather_mean<<<(N * 64 + 255) / 256, 256, 0, stream>>>(cur, adj, rs, coff, deg, aggb, N);
        sage_mfma<<<nblocks, 256, 0, stream>>>(aggb, cur, Wp + (size_t)layer * 32768,
                                               bl[layer], hb[layer], out, N, layer == 2);
        cur = hb[layer];
    }
}

// Round 5
// 192.040 us; speedup vs baseline: 25.8350x; 1.1718x over previous
//
#include <hip/hip_runtime.h>

#define F 128

typedef __attribute__((ext_vector_type(8))) short short8v;   // 8 bf16 (4 VGPR)
typedef __attribute__((ext_vector_type(4))) float f32x4;     // MFMA accumulator

__device__ __forceinline__ unsigned short f2bf(float f) {
    unsigned int u = __builtin_bit_cast(unsigned int, f);
    unsigned int r = (u + 0x7fffu + ((u >> 16) & 1u)) >> 16;
    return (unsigned short)r;
}
__device__ __forceinline__ float bf2f(unsigned int b16) {
    unsigned int u = b16 << 16;
    return __builtin_bit_cast(float, u);
}

// ---------------- init: zero deg + dtype probe (int64 vs int32) ----------------
__global__ void init_deg(const int* __restrict__ ei, int* __restrict__ flag,
                         int* __restrict__ deg, int N) {
    int i = blockIdx.x * blockDim.x + threadIdx.x;
    if (i < N) deg[i] = 0;
    if (blockIdx.x == 0) {
        __shared__ int any_nonzero;
        if (threadIdx.x == 0) any_nonzero = 0;
        __syncthreads();
        // If data is int64 (LE, values < 2^31), every odd 32-bit word is 0.
        int v = ei[2 * threadIdx.x + 1];
        if (v != 0) atomicOr(&any_nonzero, 1);
        __syncthreads();
        if (threadIdx.x == 0) *flag = (any_nonzero == 0) ? 1 : 0;  // 1 => int64
    }
}

__device__ __forceinline__ int load_src(const int* ei, int is64, int E, int e) {
    return is64 ? ei[2 * e] : ei[e];
}
__device__ __forceinline__ int load_dst(const int* ei, int is64, int E, int e) {
    return is64 ? ei[2 * (E + e)] : ei[E + e];
}

// ---------------- degree histogram + per-edge rank ----------------
__global__ void count_rank(const int* __restrict__ ei, const int* __restrict__ flag,
                           int* __restrict__ deg, int* __restrict__ rank, int E) {
    int e = blockIdx.x * blockDim.x + threadIdx.x;
    if (e >= E) return;
    int is64 = *flag;
    int d = load_dst(ei, is64, E, e);
    rank[e] = atomicAdd(&deg[d], 1);
}

// ---------------- 2-level scan: local chunks of 1024 ----------------
__global__ __launch_bounds__(1024) void scan_local(const int* __restrict__ deg,
                                                   int* __restrict__ rs,
                                                   int* __restrict__ partials, int N) {
    __shared__ int wsum[16];
    const int tid = threadIdx.x;
    const int lane = tid & 63, wid = tid >> 6;
    int i = blockIdx.x * 1024 + tid;
    int v = (i < N) ? deg[i] : 0;
    int incl = v;
#pragma unroll
    for (int d = 1; d < 64; d <<= 1) {
        int t = __shfl_up(incl, d);
        if (lane >= d) incl += t;
    }
    if (lane == 63) wsum[wid] = incl;
    __syncthreads();
    if (tid == 0) {
        int acc = 0;
#pragma unroll
        for (int w = 0; w < 16; ++w) { int t = wsum[w]; wsum[w] = acc; acc += t; }
        partials[blockIdx.x] = acc;
    }
    __syncthreads();
    if (i < N) rs[i] = wsum[wid] + (incl - v);  // chunk-local exclusive prefix
}

// scan the <=64 chunk totals with one wave -> chunk offsets
__global__ void scan_part(const int* __restrict__ partials, int* __restrict__ coff,
                          int nch) {
    int tid = threadIdx.x;
    int v = (tid < nch) ? partials[tid] : 0;
    int incl = v;
#pragma unroll
    for (int d = 1; d < 64; d <<= 1) {
        int t = __shfl_up(incl, d);
        if (tid >= d) incl += t;
    }
    coff[tid] = incl - v;  // exclusive
}

// ---------------- CSR fill (atomic-free) ----------------
__global__ void fill_adj(const int* __restrict__ ei, const int* __restrict__ flag,
                         const int* __restrict__ rs, const int* __restrict__ coff,
                         const int* __restrict__ rank, int* __restrict__ adj, int E) {
    int e = blockIdx.x * blockDim.x + threadIdx.x;
    if (e >= E) return;
    int is64 = *flag;
    int s = load_src(ei, is64, E, e);
    int d = load_dst(ei, is64, E, e);
    adj[rs[d] + coff[d >> 10] + rank[e]] = s;
}

// ---------------- fused converts: x fp32->bf16, and 3x W-pack ----------------
// Wpack[L][kt][nt][lane][i] = W[kt*32 + (lane>>4)*8 + i][nt*16 + (lane&15)]
__global__ void convert_all(const float* __restrict__ x, unsigned short* __restrict__ xb,
                            int nxblocks,
                            const float* __restrict__ Wl0, const float* __restrict__ Wr0,
                            const float* __restrict__ Wl1, const float* __restrict__ Wr1,
                            const float* __restrict__ Wl2, const float* __restrict__ Wr2,
                            unsigned short* __restrict__ Wp) {
    int b = blockIdx.x;
    if (b < nxblocks) {
        int i = b * 256 + threadIdx.x;
        float4 v = *(const float4*)(x + (size_t)i * 4);
        ushort4 o;
        o.x = f2bf(v.x); o.y = f2bf(v.y); o.z = f2bf(v.z); o.w = f2bf(v.w);
        *(ushort4*)(xb + (size_t)i * 4) = o;
        return;
    }
    int t = (b - nxblocks) * 256 + threadIdx.x;  // 0..12287
    int L = t >> 12;
    int tt = t & 4095;  // (kt*8+nt)*64 + lane
    const float* Wl = (L == 0) ? Wl0 : (L == 1) ? Wl1 : Wl2;
    const float* Wr = (L == 0) ? Wr0 : (L == 1) ? Wr1 : Wr2;
    int lane = tt & 63;
    int nt = (tt >> 6) & 7;
    int kt = (tt >> 9) & 7;
    int c = nt * 16 + (lane & 15);
    int kbase = kt * 32 + ((lane >> 4) << 3);
    unsigned short o[8];
#pragma unroll
    for (int i = 0; i < 8; ++i) {
        int k = kbase + i;
        float v = (k < 128) ? Wl[k * F + c] : Wr[(k - 128) * F + c];
        o[i] = f2bf(v);
    }
    *(uint4*)(Wp + ((size_t)L * 32768) + (size_t)tt * 8) = *(const uint4*)o;
}

// ---------------- gather-mean: 4 edges per wave-issue, 16B/lane ----------------
// one wave per node; quarter q=lane>>4 handles edges q, q+4, q+8, ...
// lane loads uint4 = 8 bf16 feats at offset (lane&15)*8
__global__ __launch_bounds__(256) void gather_mean(
    const unsigned short* __restrict__ xb, const int* __restrict__ adj,
    const int* __restrict__ rs, const int* __restrict__ coff,
    const int* __restrict__ deg, unsigned short* __restrict__ aggb, int N) {
    int n = (blockIdx.x * blockDim.x + threadIdx.x) >> 6;
    if (n >= N) return;
    const int lane = threadIdx.x & 63;
    const int q = lane >> 4, l4 = lane & 15;
    const int start = rs[n] + coff[n >> 10];
    const int d = deg[n];
    const unsigned short* xbase = xb + l4 * 8;
    float a0 = 0.f, a1 = 0.f, a2 = 0.f, a3 = 0.f;
    float a4 = 0.f, a5 = 0.f, a6 = 0.f, a7 = 0.f;
    int i = q;
    for (; i + 4 < d; i += 8) {
        int s0 = adj[start + i];
        int s1 = adj[start + i + 4];
        uint4 v0 = *(const uint4*)(xbase + (size_t)s0 * F);
        uint4 v1 = *(const uint4*)(xbase + (size_t)s1 * F);
        a0 += bf2f(v0.x & 0xffff) + bf2f(v1.x & 0xffff);
        a1 += bf2f(v0.x >> 16) + bf2f(v1.x >> 16);
        a2 += bf2f(v0.y & 0xffff) + bf2f(v1.y & 0xffff);
        a3 += bf2f(v0.y >> 16) + bf2f(v1.y >> 16);
        a4 += bf2f(v0.z & 0xffff) + bf2f(v1.z & 0xffff);
        a5 += bf2f(v0.z >> 16) + bf2f(v1.z >> 16);
        a6 += bf2f(v0.w & 0xffff) + bf2f(v1.w & 0xffff);
        a7 += bf2f(v0.w >> 16) + bf2f(v1.w >> 16);
    }
    if (i < d) {  // at most one residual edge per quarter
        int s = adj[start + i];
        uint4 v = *(const uint4*)(xbase + (size_t)s * F);
        a0 += bf2f(v.x & 0xffff);
        a1 += bf2f(v.x >> 16);
        a2 += bf2f(v.y & 0xffff);
        a3 += bf2f(v.y >> 16);
        a4 += bf2f(v.z & 0xffff);
        a5 += bf2f(v.z >> 16);
        a6 += bf2f(v.w & 0xffff);
        a7 += bf2f(v.w >> 16);
    }
    // combine quarters: q ^ 1 (xor 16), then halves (xor 32)
    a0 += __shfl_xor(a0, 16); a0 += __shfl_xor(a0, 32);
    a1 += __shfl_xor(a1, 16); a1 += __shfl_xor(a1, 32);
    a2 += __shfl_xor(a2, 16); a2 += __shfl_xor(a2, 32);
    a3 += __shfl_xor(a3, 16); a3 += __shfl_xor(a3, 32);
    a4 += __shfl_xor(a4, 16); a4 += __shfl_xor(a4, 32);
    a5 += __shfl_xor(a5, 16); a5 += __shfl_xor(a5, 32);
    a6 += __shfl_xor(a6, 16); a6 += __shfl_xor(a6, 32);
    a7 += __shfl_xor(a7, 16); a7 += __shfl_xor(a7, 32);
    if (q == 0) {
        float inv = 1.0f / fmaxf((float)d, 1.0f);
        uint4 o;
        o.x = ((unsigned int)f2bf(a1 * inv) << 16) | f2bf(a0 * inv);
        o.y = ((unsigned int)f2bf(a3 * inv) << 16) | f2bf(a2 * inv);
        o.z = ((unsigned int)f2bf(a5 * inv) << 16) | f2bf(a4 * inv);
        o.w = ((unsigned int)f2bf(a7 * inv) << 16) | f2bf(a6 * inv);
        *(uint4*)(aggb + (size_t)n * F + l4 * 8) = o;
    }
}

// ---------------- MFMA layer: out = [agg|x] @ Wpack + bl (+relu) ----------------
// 512 threads = 8 waves/block; W staged once in 64KB LDS, shared by all waves.
// Each wave: 16 rows x 128 cols, K=256 (8 ktiles of 32).
__global__ __launch_bounds__(512) void sage_mfma(
    const unsigned short* __restrict__ aggb, const unsigned short* __restrict__ xb,
    const unsigned short* __restrict__ Wpack, const float* __restrict__ bl,
    unsigned short* __restrict__ outb, float* __restrict__ outf,
    int N, int final_layer) {
    __shared__ unsigned short sW[32768];  // 64 KB
    {
        const uint4* srcv = (const uint4*)Wpack;
        uint4* dstv = (uint4*)sW;
#pragma unroll
        for (int t = 0; t < 8; ++t)
            dstv[threadIdx.x + t * 512] = srcv[threadIdx.x + t * 512];
    }
    __syncthreads();

    const int wid = threadIdx.x >> 6;
    const int lane = threadIdx.x & 63;
    const int row0 = (blockIdx.x * 8 + wid) * 16;
    if (row0 >= N) return;  // after barrier: no deadlock

    const int rA = row0 + (lane & 15);
    const int kidx = (lane >> 4) << 3;  // 0,8,16,24

    f32x4 acc[8];
#pragma unroll
    for (int nt = 0; nt < 8; ++nt) acc[nt] = (f32x4){0.f, 0.f, 0.f, 0.f};

    const unsigned short* arow_a = aggb + (size_t)rA * F + kidx;
    const unsigned short* arow_x = xb + (size_t)rA * F + kidx;

#pragma unroll
    for (int kt = 0; kt < 8; ++kt) {
        const unsigned short* ap = (kt < 4) ? (arow_a + kt * 32) : (arow_x + (kt - 4) * 32);
        short8v a = *(const short8v*)ap;
#pragma unroll
        for (int nt = 0; nt < 8; ++nt) {
            short8v b = *(const short8v*)(sW + ((kt * 8 + nt) * 64 + lane) * 8);
            acc[nt] = __builtin_amdgcn_mfma_f32_16x16x32_bf16(a, b, acc[nt], 0, 0, 0);
        }
    }

    // C/D layout: col = lane&15, row = (lane>>4)*4 + reg   [m89-verified]
    const int c0 = lane & 15;
    const int r0 = row0 + ((lane >> 4) << 2);
#pragma unroll
    for (int nt = 0; nt < 8; ++nt) {
        const int col = nt * 16 + c0;
        const float b = bl[col];
#pragma unroll
        for (int reg = 0; reg < 4; ++reg) {
            const int r = r0 + reg;
            float v = acc[nt][reg] + b;
            if (!final_layer) {
                v = fmaxf(v, 0.f);
                outb[(size_t)r * F + col] = f2bf(v);
            } else {
                outf[(size_t)r * F + col] = v;
            }
        }
    }
}

extern "C" void kernel_launch(void* const* d_in, const int* in_sizes, int n_in,
                              void* d_out, int out_size, void* d_ws, size_t ws_size,
                              hipStream_t stream) {
    const float* x = (const float*)d_in[0];
    const int* ei = (const int*)d_in[1];
    const int E = in_sizes[1] / 2;
    const int N = in_sizes[0] / F;
    const int NCH = (N + 1023) / 1024;

    const float* Wl[3] = {(const float*)d_in[2], (const float*)d_in[5], (const float*)d_in[8]};
    const float* bl[3] = {(const float*)d_in[3], (const float*)d_in[6], (const float*)d_in[9]};
    const float* Wr[3] = {(const float*)d_in[4], (const float*)d_in[7], (const float*)d_in[10]};
    float* out = (float*)d_out;

    char* ws = (char*)d_ws;
    size_t off = 0;
    auto alloc = [&](size_t bytes) {
        size_t o = off;
        off = (off + bytes + 255) & ~(size_t)255;
        return o;
    };
    int* flag = (int*)(ws + alloc(4));
    int* deg = (int*)(ws + alloc((size_t)N * 4));
    int* rs = (int*)(ws + alloc((size_t)N * 4));
    int* partials = (int*)(ws + alloc(64 * 4));
    int* coff = (int*)(ws + alloc(64 * 4));
    int* rank = (int*)(ws + alloc((size_t)E * 4));
    int* adj = (int*)(ws + alloc((size_t)E * 4));
    unsigned short* xb = (unsigned short*)(ws + alloc((size_t)N * F * 2));
    unsigned short* aggb = (unsigned short*)(ws + alloc((size_t)N * F * 2));
    unsigned short* h1b = (unsigned short*)(ws + alloc((size_t)N * F * 2));
    unsigned short* h2b = (unsigned short*)(ws + alloc((size_t)N * F * 2));
    unsigned short* Wp = (unsigned short*)(ws + alloc((size_t)3 * 4096 * 8 * 2));

    // ---- CSR build (once) ----
    init_deg<<<(N + 255) / 256, 256, 0, stream>>>(ei, flag, deg, N);
    count_rank<<<(E + 255) / 256, 256, 0, stream>>>(ei, flag, deg, rank, E);
    scan_local<<<NCH, 1024, 0, stream>>>(deg, rs, partials, N);
    scan_part<<<1, 64, 0, stream>>>(partials, coff, NCH);
    fill_adj<<<(E + 255) / 256, 256, 0, stream>>>(ei, flag, rs, coff, rank, adj, E);

    // ---- conversions (one launch) ----
    int nxblocks = (N * F / 4 + 255) / 256;
    convert_all<<<nxblocks + 48, 256, 0, stream>>>(x, xb, nxblocks,
                                                   Wl[0], Wr[0], Wl[1], Wr[1], Wl[2], Wr[2],
                                                   Wp);

    // ---- layers ----
    const unsigned short* cur = xb;
    unsigned short* hb[3] = {h1b, h2b, nullptr};
    int nwaves = (N + 15) / 16;
    int nblocks_m = (nwaves + 7) / 8;
    for (int layer = 0; layer < 3; ++layer) {
        gather_mean<<<(N * 64 + 255) / 256, 256, 0, stream>>>(cur, adj, rs, coff, deg, aggb, N);
        sage_mfma<<<nblocks_m, 512, 0, stream>>>(aggb, cur, Wp + (size_t)layer * 32768,
                                                 bl[layer], hb[layer], out, N, layer == 2);
        cur = hb[layer];
    }
}

// Round 6
// 191.285 us; speedup vs baseline: 25.9370x; 1.0039x over previous
//
#include <hip/hip_runtime.h>

#define F 128

typedef __attribute__((ext_vector_type(8))) short short8v;   // 8 bf16 (4 VGPR)
typedef __attribute__((ext_vector_type(4))) float f32x4;     // MFMA accumulator

__device__ __forceinline__ unsigned short f2bf(float f) {
    unsigned int u = __builtin_bit_cast(unsigned int, f);
    unsigned int r = (u + 0x7fffu + ((u >> 16) & 1u)) >> 16;
    return (unsigned short)r;
}
__device__ __forceinline__ float bf2f(unsigned int b16) {
    unsigned int u = b16 << 16;
    return __builtin_bit_cast(float, u);
}

__device__ __forceinline__ int load_src(const int* ei, int is64, int E, int e) {
    return is64 ? ei[2 * e] : ei[e];
}
__device__ __forceinline__ int load_dst(const int* ei, int is64, int E, int e) {
    return is64 ? ei[2 * (E + e)] : ei[E + e];
}

// ---------------- prep: zero deg + dtype probe + x->bf16 + 3x W-pack ----------------
// block layout: [0, ndegb) deg-zero (+flag probe in block 0)
//               [ndegb, ndegb+nxb) x convert
//               [ndegb+nxb, +48)   W pack (3 layers x 4096 threads)
__global__ void prep(const int* __restrict__ ei, int* __restrict__ flag,
                     int* __restrict__ deg, int N,
                     const float* __restrict__ x, unsigned short* __restrict__ xb,
                     int ndegb, int nxb,
                     const float* __restrict__ Wl0, const float* __restrict__ Wr0,
                     const float* __restrict__ Wl1, const float* __restrict__ Wr1,
                     const float* __restrict__ Wl2, const float* __restrict__ Wr2,
                     unsigned short* __restrict__ Wp) {
    int b = blockIdx.x;
    if (b < ndegb) {
        int i = b * 256 + threadIdx.x;
        if (i < N) deg[i] = 0;
        if (b == 0) {
            __shared__ int any_nonzero;
            if (threadIdx.x == 0) any_nonzero = 0;
            __syncthreads();
            // int64 (LE, values < 2^31) => every odd 32-bit word is 0.
            int v = ei[2 * threadIdx.x + 1];
            if (v != 0) atomicOr(&any_nonzero, 1);
            __syncthreads();
            if (threadIdx.x == 0) *flag = (any_nonzero == 0) ? 1 : 0;  // 1 => int64
        }
        return;
    }
    if (b < ndegb + nxb) {
        int i = (b - ndegb) * 256 + threadIdx.x;
        float4 v = *(const float4*)(x + (size_t)i * 4);
        ushort4 o;
        o.x = f2bf(v.x); o.y = f2bf(v.y); o.z = f2bf(v.z); o.w = f2bf(v.w);
        *(ushort4*)(xb + (size_t)i * 4) = o;
        return;
    }
    // W pack: Wp[L][kt][nt][lane][i] = W[kt*32 + (lane>>4)*8 + i][nt*16 + (lane&15)]
    int t = (b - ndegb - nxb) * 256 + threadIdx.x;  // 0..12287
    int L = t >> 12;
    int tt = t & 4095;
    const float* Wl = (L == 0) ? Wl0 : (L == 1) ? Wl1 : Wl2;
    const float* Wr = (L == 0) ? Wr0 : (L == 1) ? Wr1 : Wr2;
    int lane = tt & 63;
    int nt = (tt >> 6) & 7;
    int kt = (tt >> 9) & 7;
    int c = nt * 16 + (lane & 15);
    int kbase = kt * 32 + ((lane >> 4) << 3);
    unsigned short o[8];
#pragma unroll
    for (int i = 0; i < 8; ++i) {
        int k = kbase + i;
        float v = (k < 128) ? Wl[k * F + c] : Wr[(k - 128) * F + c];
        o[i] = f2bf(v);
    }
    *(uint4*)(Wp + ((size_t)L * 32768) + (size_t)tt * 8) = *(const uint4*)o;
}

// ---------------- degree histogram + per-edge rank ----------------
__global__ void count_rank(const int* __restrict__ ei, const int* __restrict__ flag,
                           int* __restrict__ deg, int* __restrict__ rank, int E) {
    int e = blockIdx.x * blockDim.x + threadIdx.x;
    if (e >= E) return;
    int is64 = *flag;
    int d = load_dst(ei, is64, E, e);
    rank[e] = atomicAdd(&deg[d], 1);
}

// ---------------- 2-level scan: local chunks of 1024 ----------------
__global__ __launch_bounds__(1024) void scan_local(const int* __restrict__ deg,
                                                   int* __restrict__ rs,
                                                   int* __restrict__ partials, int N) {
    __shared__ int wsum[16];
    const int tid = threadIdx.x;
    const int lane = tid & 63, wid = tid >> 6;
    int i = blockIdx.x * 1024 + tid;
    int v = (i < N) ? deg[i] : 0;
    int incl = v;
#pragma unroll
    for (int d = 1; d < 64; d <<= 1) {
        int t = __shfl_up(incl, d);
        if (lane >= d) incl += t;
    }
    if (lane == 63) wsum[wid] = incl;
    __syncthreads();
    if (tid == 0) {
        int acc = 0;
#pragma unroll
        for (int w = 0; w < 16; ++w) { int t = wsum[w]; wsum[w] = acc; acc += t; }
        partials[blockIdx.x] = acc;
    }
    __syncthreads();
    if (i < N) rs[i] = wsum[wid] + (incl - v);  // chunk-local exclusive prefix
}

// scan the <=64 chunk totals with one wave -> chunk offsets
__global__ void scan_part(const int* __restrict__ partials, int* __restrict__ coff,
                          int nch) {
    int tid = threadIdx.x;
    int v = (tid < nch) ? partials[tid] : 0;
    int incl = v;
#pragma unroll
    for (int d = 1; d < 64; d <<= 1) {
        int t = __shfl_up(incl, d);
        if (tid >= d) incl += t;
    }
    coff[tid] = incl - v;  // exclusive
}

// ---------------- CSR fill (atomic-free) ----------------
__global__ void fill_adj(const int* __restrict__ ei, const int* __restrict__ flag,
                         const int* __restrict__ rs, const int* __restrict__ coff,
                         const int* __restrict__ rank, int* __restrict__ adj, int E) {
    int e = blockIdx.x * blockDim.x + threadIdx.x;
    if (e >= E) return;
    int is64 = *flag;
    int s = load_src(ei, is64, E, e);
    int d = load_dst(ei, is64, E, e);
    adj[rs[d] + coff[d >> 10] + rank[e]] = s;
}

// ---------------- gather-mean: 4 edges per quarter-iteration, 16B/lane ----------------
// one wave per node; quarter q=lane>>4 handles edges q, q+4, q+8, ...
// lane loads uint4 = 8 bf16 feats at offset (lane&15)*8; unroll 4 (4 loads in flight)
__global__ __launch_bounds__(256) void gather_mean(
    const unsigned short* __restrict__ xb, const int* __restrict__ adj,
    const int* __restrict__ rs, const int* __restrict__ coff,
    const int* __restrict__ deg, unsigned short* __restrict__ aggb, int N) {
    int n = (blockIdx.x * blockDim.x + threadIdx.x) >> 6;
    if (n >= N) return;
    const int lane = threadIdx.x & 63;
    const int q = lane >> 4, l4 = lane & 15;
    const int start = rs[n] + coff[n >> 10];
    const int d = deg[n];
    const unsigned short* xbase = xb + l4 * 8;
    float a0 = 0.f, a1 = 0.f, a2 = 0.f, a3 = 0.f;
    float a4 = 0.f, a5 = 0.f, a6 = 0.f, a7 = 0.f;
    int i = q;
    for (; i + 12 < d; i += 16) {
        int s0 = adj[start + i];
        int s1 = adj[start + i + 4];
        int s2 = adj[start + i + 8];
        int s3 = adj[start + i + 12];
        uint4 v0 = *(const uint4*)(xbase + (size_t)s0 * F);
        uint4 v1 = *(const uint4*)(xbase + (size_t)s1 * F);
        uint4 v2 = *(const uint4*)(xbase + (size_t)s2 * F);
        uint4 v3 = *(const uint4*)(xbase + (size_t)s3 * F);
        a0 += bf2f(v0.x & 0xffff) + bf2f(v1.x & 0xffff) + bf2f(v2.x & 0xffff) + bf2f(v3.x & 0xffff);
        a1 += bf2f(v0.x >> 16) + bf2f(v1.x >> 16) + bf2f(v2.x >> 16) + bf2f(v3.x >> 16);
        a2 += bf2f(v0.y & 0xffff) + bf2f(v1.y & 0xffff) + bf2f(v2.y & 0xffff) + bf2f(v3.y & 0xffff);
        a3 += bf2f(v0.y >> 16) + bf2f(v1.y >> 16) + bf2f(v2.y >> 16) + bf2f(v3.y >> 16);
        a4 += bf2f(v0.z & 0xffff) + bf2f(v1.z & 0xffff) + bf2f(v2.z & 0xffff) + bf2f(v3.z & 0xffff);
        a5 += bf2f(v0.z >> 16) + bf2f(v1.z >> 16) + bf2f(v2.z >> 16) + bf2f(v3.z >> 16);
        a6 += bf2f(v0.w & 0xffff) + bf2f(v1.w & 0xffff) + bf2f(v2.w & 0xffff) + bf2f(v3.w & 0xffff);
        a7 += bf2f(v0.w >> 16) + bf2f(v1.w >> 16) + bf2f(v2.w >> 16) + bf2f(v3.w >> 16);
    }
    for (; i < d; i += 4) {
        int s = adj[start + i];
        uint4 v = *(const uint4*)(xbase + (size_t)s * F);
        a0 += bf2f(v.x & 0xffff);
        a1 += bf2f(v.x >> 16);
        a2 += bf2f(v.y & 0xffff);
        a3 += bf2f(v.y >> 16);
        a4 += bf2f(v.z & 0xffff);
        a5 += bf2f(v.z >> 16);
        a6 += bf2f(v.w & 0xffff);
        a7 += bf2f(v.w >> 16);
    }
    // combine quarters: xor 16, then xor 32
    a0 += __shfl_xor(a0, 16); a0 += __shfl_xor(a0, 32);
    a1 += __shfl_xor(a1, 16); a1 += __shfl_xor(a1, 32);
    a2 += __shfl_xor(a2, 16); a2 += __shfl_xor(a2, 32);
    a3 += __shfl_xor(a3, 16); a3 += __shfl_xor(a3, 32);
    a4 += __shfl_xor(a4, 16); a4 += __shfl_xor(a4, 32);
    a5 += __shfl_xor(a5, 16); a5 += __shfl_xor(a5, 32);
    a6 += __shfl_xor(a6, 16); a6 += __shfl_xor(a6, 32);
    a7 += __shfl_xor(a7, 16); a7 += __shfl_xor(a7, 32);
    if (q == 0) {
        float inv = 1.0f / fmaxf((float)d, 1.0f);
        uint4 o;
        o.x = ((unsigned int)f2bf(a1 * inv) << 16) | f2bf(a0 * inv);
        o.y = ((unsigned int)f2bf(a3 * inv) << 16) | f2bf(a2 * inv);
        o.z = ((unsigned int)f2bf(a5 * inv) << 16) | f2bf(a4 * inv);
        o.w = ((unsigned int)f2bf(a7 * inv) << 16) | f2bf(a6 * inv);
        *(uint4*)(aggb + (size_t)n * F + l4 * 8) = o;
    }
}

// ---------------- MFMA layer: out = [agg|x] @ Wpack + bl (+relu) ----------------
// 512 threads = 8 waves/block; W staged once in 64KB LDS, shared by all waves.
// A-frags prefetched to registers BEFORE the staging barrier (latency overlap).
// Each wave: 16 rows x 128 cols, K=256 (8 ktiles of 32). Requires N % 16 == 0.
__global__ __launch_bounds__(512) void sage_mfma(
    const unsigned short* __restrict__ aggb, const unsigned short* __restrict__ xb,
    const unsigned short* __restrict__ Wpack, const float* __restrict__ bl,
    unsigned short* __restrict__ outb, float* __restrict__ outf,
    int N, int final_layer) {
    __shared__ unsigned short sW[32768];  // 64 KB

    const int wid = threadIdx.x >> 6;
    const int lane = threadIdx.x & 63;
    const int row0 = (blockIdx.x * 8 + wid) * 16;
    const bool active = (row0 < N);

    // prefetch A fragments (global) before LDS staging so the latency overlaps
    short8v a[8];
    if (active) {
        const int rA = row0 + (lane & 15);
        const int kidx = (lane >> 4) << 3;  // 0,8,16,24
        const unsigned short* arow_a = aggb + (size_t)rA * F + kidx;
        const unsigned short* arow_x = xb + (size_t)rA * F + kidx;
#pragma unroll
        for (int kt = 0; kt < 4; ++kt) a[kt] = *(const short8v*)(arow_a + kt * 32);
#pragma unroll
        for (int kt = 4; kt < 8; ++kt) a[kt] = *(const short8v*)(arow_x + (kt - 4) * 32);
    }

    {
        const uint4* srcv = (const uint4*)Wpack;
        uint4* dstv = (uint4*)sW;
#pragma unroll
        for (int t = 0; t < 8; ++t)
            dstv[threadIdx.x + t * 512] = srcv[threadIdx.x + t * 512];
    }
    __syncthreads();
    if (!active) return;

    f32x4 acc[8];
#pragma unroll
    for (int nt = 0; nt < 8; ++nt) acc[nt] = (f32x4){0.f, 0.f, 0.f, 0.f};

#pragma unroll
    for (int kt = 0; kt < 8; ++kt) {
#pragma unroll
        for (int nt = 0; nt < 8; ++nt) {
            short8v b = *(const short8v*)(sW + ((kt * 8 + nt) * 64 + lane) * 8);
            acc[nt] = __builtin_amdgcn_mfma_f32_16x16x32_bf16(a[kt], b, acc[nt], 0, 0, 0);
        }
    }

    // C/D layout: col = lane&15, row = (lane>>4)*4 + reg   [m89-verified]
    const int c0 = lane & 15;
    const int r0 = row0 + ((lane >> 4) << 2);
#pragma unroll
    for (int nt = 0; nt < 8; ++nt) {
        const int col = nt * 16 + c0;
        const float b = bl[col];
#pragma unroll
        for (int reg = 0; reg < 4; ++reg) {
            const int r = r0 + reg;
            float v = acc[nt][reg] + b;
            if (!final_layer) {
                v = fmaxf(v, 0.f);
                outb[(size_t)r * F + col] = f2bf(v);
            } else {
                outf[(size_t)r * F + col] = v;
            }
        }
    }
}

extern "C" void kernel_launch(void* const* d_in, const int* in_sizes, int n_in,
                              void* d_out, int out_size, void* d_ws, size_t ws_size,
                              hipStream_t stream) {
    const float* x = (const float*)d_in[0];
    const int* ei = (const int*)d_in[1];
    const int E = in_sizes[1] / 2;
    const int N = in_sizes[0] / F;
    const int NCH = (N + 1023) / 1024;

    const float* Wl[3] = {(const float*)d_in[2], (const float*)d_in[5], (const float*)d_in[8]};
    const float* bl[3] = {(const float*)d_in[3], (const float*)d_in[6], (const float*)d_in[9]};
    const float* Wr[3] = {(const float*)d_in[4], (const float*)d_in[7], (const float*)d_in[10]};
    float* out = (float*)d_out;

    char* ws = (char*)d_ws;
    size_t off = 0;
    auto alloc = [&](size_t bytes) {
        size_t o = off;
        off = (off + bytes + 255) & ~(size_t)255;
        return o;
    };
    int* flag = (int*)(ws + alloc(4));
    int* deg = (int*)(ws + alloc((size_t)N * 4));
    int* rs = (int*)(ws + alloc((size_t)N * 4));
    int* partials = (int*)(ws + alloc(64 * 4));
    int* coff = (int*)(ws + alloc(64 * 4));
    int* rank = (int*)(ws + alloc((size_t)E * 4));
    int* adj = (int*)(ws + alloc((size_t)E * 4));
    unsigned short* xb = (unsigned short*)(ws + alloc((size_t)N * F * 2));
    unsigned short* aggb = (unsigned short*)(ws + alloc((size_t)N * F * 2));
    unsigned short* h1b = (unsigned short*)(ws + alloc((size_t)N * F * 2));
    unsigned short* h2b = (unsigned short*)(ws + alloc((size_t)N * F * 2));
    unsigned short* Wp = (unsigned short*)(ws + alloc((size_t)3 * 4096 * 8 * 2));

    // ---- prep: deg zero + flag + x->bf16 + W pack (one launch) ----
    int ndegb = (N + 255) / 256;
    int nxb = (N * F / 4 + 255) / 256;
    prep<<<ndegb + nxb + 48, 256, 0, stream>>>(ei, flag, deg, N, x, xb, ndegb, nxb,
                                               Wl[0], Wr[0], Wl[1], Wr[1], Wl[2], Wr[2], Wp);

    // ---- CSR build ----
    count_rank<<<(E + 255) / 256, 256, 0, stream>>>(ei, flag, deg, rank, E);
    scan_local<<<NCH, 1024, 0, stream>>>(deg, rs, partials, N);
    scan_part<<<1, 64, 0, stream>>>(partials, coff, NCH);
    fill_adj<<<(E + 255) / 256, 256, 0, stream>>>(ei, flag, rs, coff, rank, adj, E);

    // ---- layers ----
    const unsigned short* cur = xb;
    unsigned short* hb[3] = {h1b, h2b, nullptr};
    int nwaves = (N + 15) / 16;
    int nblocks_m = (nwaves + 7) / 8;
    for (int layer = 0; layer < 3; ++layer) {
        gather_mean<<<(N * 64 + 255) / 256, 256, 0, stream>>>(cur, adj, rs, coff, deg, aggb, N);
        sage_mfma<<<nblocks_m, 512, 0, stream>>>(aggb, cur, Wp + (size_t)layer * 32768,
                                                 bl[layer], hb[layer], out, N, layer == 2);
        cur = hb[layer];
    }
}